// Round 10
// baseline (34.257 us; speedup 1.0000x reference)
//
#include <hip/hip_runtime.h>

// ZNCC 5x5, zero-padded, count_include_pad means.
// x,y: (4,3,512,512) f32 -> out: (4,1,512,512) f32
// Round 10: R9 pipelined structure (double-buffered LDS, register-prefetch of
// next channel before compute, hoisted staging addresses) at HALF the tile:
// 64x16 tiles, 4 px/thread (2col x 2row) -> grid 1024 = 4 blocks/CU
// = 16 waves/CU (2x R9's residency). LDS 24.6KB/block. VGPR capped at 128.

constexpr int W  = 512, H = 512, C = 3, NB = 4;
constexpr int PLANE = H * W;
constexpr int TW = 64, TH = 16, HALO = 2;
constexpr int LW = TW + 2 * HALO;   // 68
constexpr int LH = TH + 2 * HALO;   // 20
constexpr int LSZ  = LW * LH;       // 1360
constexpr int LPAD = 1536;          // 6 chunks * 256 threads
constexpr int NPF  = 6;             // prefetch regs per array per thread

__device__ __forceinline__ void prefetch_plane(const float* __restrict__ pb,
                                               const int* goff, const float* fm,
                                               float* r) {
    #pragma unroll
    for (int k = 0; k < NPF; ++k) r[k] = pb[goff[k]] * fm[k];
}

__device__ __forceinline__ void write_tile(float* __restrict__ dst,
                                           const float* r, int tid) {
    #pragma unroll
    for (int k = 0; k < NPF; ++k) dst[tid + 256 * k] = r[k];
}

// Rolling 5x6 register window over a staged 20x68 tile; 2 output rows/thread.
__device__ __forceinline__ void compute_channel(const float* __restrict__ bxs,
                                                const float* __restrict__ bys,
                                                int ry, int cx,
                                                float* ch0, float* ch1) {
    const float EPS = 1e-4f;
    float bx[5][6], by[5][6];
    float csx[6], csy[6];

    #pragma unroll
    for (int k = 0; k < 4; ++k) {
        const int base = (2 * ry + k) * LW + cx;
        const float2 u0 = *reinterpret_cast<const float2*>(&bxs[base]);
        const float2 u1 = *reinterpret_cast<const float2*>(&bxs[base + 2]);
        const float2 u2 = *reinterpret_cast<const float2*>(&bxs[base + 4]);
        const float2 v0 = *reinterpret_cast<const float2*>(&bys[base]);
        const float2 v1 = *reinterpret_cast<const float2*>(&bys[base + 2]);
        const float2 v2 = *reinterpret_cast<const float2*>(&bys[base + 4]);
        bx[k][0] = u0.x; bx[k][1] = u0.y; bx[k][2] = u1.x;
        bx[k][3] = u1.y; bx[k][4] = u2.x; bx[k][5] = u2.y;
        by[k][0] = v0.x; by[k][1] = v0.y; by[k][2] = v1.x;
        by[k][3] = v1.y; by[k][4] = v2.x; by[k][5] = v2.y;
        #pragma unroll
        for (int j = 0; j < 6; ++j) {
            if (k == 0) { csx[j] = bx[0][j];  csy[j] = by[0][j]; }
            else        { csx[j] += bx[k][j]; csy[j] += by[k][j]; }
        }
    }

    #pragma unroll
    for (int o = 0; o < 2; ++o) {
        const int sN   = (o + 4) % 5;
        const int base = (2 * ry + o + 4) * LW + cx;
        {
            const float2 u0 = *reinterpret_cast<const float2*>(&bxs[base]);
            const float2 u1 = *reinterpret_cast<const float2*>(&bxs[base + 2]);
            const float2 u2 = *reinterpret_cast<const float2*>(&bxs[base + 4]);
            const float2 v0 = *reinterpret_cast<const float2*>(&bys[base]);
            const float2 v1 = *reinterpret_cast<const float2*>(&bys[base + 2]);
            const float2 v2 = *reinterpret_cast<const float2*>(&bys[base + 4]);
            bx[sN][0] = u0.x; bx[sN][1] = u0.y; bx[sN][2] = u1.x;
            bx[sN][3] = u1.y; bx[sN][4] = u2.x; bx[sN][5] = u2.y;
            by[sN][0] = v0.x; by[sN][1] = v0.y; by[sN][2] = v1.x;
            by[sN][3] = v1.y; by[sN][4] = v2.x; by[sN][5] = v2.y;
        }
        #pragma unroll
        for (int j = 0; j < 6; ++j) { csx[j] += bx[sN][j]; csy[j] += by[sN][j]; }

        const float m4x = csx[1] + csx[2] + csx[3] + csx[4];
        const float m4y = csy[1] + csy[2] + csy[3] + csy[4];
        const float mx0 = (m4x + csx[0]) * (1.f / 25.f);
        const float mx1 = (m4x + csx[5]) * (1.f / 25.f);
        const float my0 = (m4y + csy[0]) * (1.f / 25.f);
        const float my1 = (m4y + csy[5]) * (1.f / 25.f);

        float a0 = 0.f, a1 = 0.f;
        #pragma unroll
        for (int k = 0; k < 5; ++k) {
            const int s = (o + k) % 5;
            #pragma unroll
            for (int j = 0; j < 5; ++j) {
                {
                    const float dx  = bx[s][j] - mx0;
                    const float dy  = by[s][j] - my0;
                    const float num = fabsf(dx * dy) + EPS;
                    const float den = (dx * dx + EPS) * (dy * dy + EPS);
                    a0 += num * __builtin_amdgcn_rsqf(den);
                }
                {
                    const float dx  = bx[s][j + 1] - mx1;
                    const float dy  = by[s][j + 1] - my1;
                    const float num = fabsf(dx * dy) + EPS;
                    const float den = (dx * dx + EPS) * (dy * dy + EPS);
                    a1 += num * __builtin_amdgcn_rsqf(den);
                }
            }
        }
        ch0[o] += fminf(fmaxf(a0 * (1.f / 25.f), 0.f), 1.f);
        ch1[o] += fminf(fmaxf(a1 * (1.f / 25.f), 0.f), 1.f);

        const int sO = o % 5;
        #pragma unroll
        for (int j = 0; j < 6; ++j) { csx[j] -= bx[sO][j]; csy[j] -= by[sO][j]; }
    }
}

__global__ __launch_bounds__(256, 4)
void zncc_kernel(const float* __restrict__ x,
                 const float* __restrict__ y,
                 float* __restrict__ out) {
    __shared__ float sb[2][2][LPAD];    // [buf][x=0/y=1][...]  24576 B

    const int tid = threadIdx.x;
    const int tx  = tid & 31;           // 32 col-pairs -> 64 cols
    const int ry  = tid >> 5;           // 0..7 -> rows 2*ry, 2*ry+1
    const int cx  = 2 * tx;
    const int w0  = blockIdx.x * TW;
    const int h0  = blockIdx.y * TH;
    const int b   = blockIdx.z;

    // ---- staging address math, once (reused for all 3 channels) ----
    int   goff[NPF];
    float fm[NPF];
    #pragma unroll
    for (int k = 0; k < NPF; ++k) {
        const int i  = tid + 256 * k;
        const int l  = i / LW;
        const int m  = i - l * LW;
        const int gr = h0 + l - HALO;
        const int gc = w0 + m - HALO;
        const bool ok = (i < LSZ) && ((unsigned)gr < (unsigned)H) &&
                        ((unsigned)gc < (unsigned)W);
        goff[k] = ok ? gr * W + gc : 0;
        fm[k]   = ok ? 1.f : 0.f;
    }

    const float* xb0 = x + (size_t)(b * C) * PLANE;
    const float* yb0 = y + (size_t)(b * C) * PLANE;

    float ch0[2] = {0.f, 0.f};
    float ch1[2] = {0.f, 0.f};
    float px[NPF], py[NPF];

    // ---- stage channel 0 -> buf0 ----
    prefetch_plane(xb0, goff, fm, px);
    prefetch_plane(yb0, goff, fm, py);
    write_tile(&sb[0][0][0], px, tid);
    write_tile(&sb[0][1][0], py, tid);
    __syncthreads();

    // ---- channel 0: prefetch ch1, compute from buf0, write buf1 ----
    prefetch_plane(xb0 + PLANE, goff, fm, px);
    prefetch_plane(yb0 + PLANE, goff, fm, py);
    compute_channel(&sb[0][0][0], &sb[0][1][0], ry, cx, ch0, ch1);
    write_tile(&sb[1][0][0], px, tid);
    write_tile(&sb[1][1][0], py, tid);
    __syncthreads();

    // ---- channel 1: prefetch ch2, compute from buf1, write buf0 ----
    prefetch_plane(xb0 + 2 * PLANE, goff, fm, px);
    prefetch_plane(yb0 + 2 * PLANE, goff, fm, py);
    compute_channel(&sb[1][0][0], &sb[1][1][0], ry, cx, ch0, ch1);
    write_tile(&sb[0][0][0], px, tid);
    write_tile(&sb[0][1][0], py, tid);
    __syncthreads();

    // ---- channel 2: compute from buf0 ----
    compute_channel(&sb[0][0][0], &sb[0][1][0], ry, cx, ch0, ch1);

    // ---- write 2x2 output strip ----
    #pragma unroll
    for (int o = 0; o < 2; ++o) {
        float2 v;
        v.x = ch0[o] * (1.f / 3.f);
        v.y = ch1[o] * (1.f / 3.f);
        *reinterpret_cast<float2*>(
            &out[((size_t)b * H + h0 + 2 * ry + o) * W + w0 + cx]) = v;
    }
}

extern "C" void kernel_launch(void* const* d_in, const int* in_sizes, int n_in,
                              void* d_out, int out_size, void* d_ws, size_t ws_size,
                              hipStream_t stream) {
    const float* x = (const float*)d_in[0];
    const float* y = (const float*)d_in[1];
    float* out = (float*)d_out;
    dim3 grid(W / TW, H / TH, NB);   // 8, 32, 4 = 1024 blocks (4 per CU)
    zncc_kernel<<<grid, dim3(256), 0, stream>>>(x, y, out);
}

// Round 11
// 30.234 us; speedup vs baseline: 1.1331x; 1.1331x over previous
//
#include <hip/hip_runtime.h>

// ZNCC 5x5, zero-padded, count_include_pad means.
// x,y: (4,3,512,512) f32 -> out: (4,1,512,512) f32
// Round 11: R9 structure (64x32 tile, pipelined dbuf staging) + packed-FP32:
// LDS stores interleaved (x,y) pairs; window/colsum/mean/term math done on
// float2 ext-vectors so LLVM selects v_pk_{add,mul,fma}_f32 (gfx90a+ packed
// FP32, full rate). Per term: 6 VALU + 1 rsq vs scalar 8 + 1, LDS instrs
// halved (3x ds_read_b128 per row serves both images). R10 proved occupancy
// is not the limiter (2x waves -> +-0%); this attacks per-CU issue count.

constexpr int W  = 512, H = 512, C = 3, NB = 4;
constexpr int PLANE = H * W;
constexpr int TW = 64, TH = 32, HALO = 2;
constexpr int LW = TW + 2 * HALO;   // 68 pairs per row
constexpr int LH = TH + 2 * HALO;   // 36
constexpr int LSZ  = LW * LH;       // 2448 pairs
constexpr int LPAD = 2560;          // 10 chunks * 256 threads
constexpr int NPF  = 10;

typedef float f2 __attribute__((ext_vector_type(2)));

__device__ __forceinline__ void prefetch_plane(const float* __restrict__ xb,
                                               const float* __restrict__ yb,
                                               const int* goff, const float* fm,
                                               float* px, float* py) {
    #pragma unroll
    for (int k = 0; k < NPF; ++k) {
        px[k] = xb[goff[k]] * fm[k];
        py[k] = yb[goff[k]] * fm[k];
    }
}

__device__ __forceinline__ void write_tile(f2* __restrict__ dst,
                                           const float* px, const float* py,
                                           int tid) {
    #pragma unroll
    for (int k = 0; k < NPF; ++k) {
        f2 v; v.x = px[k]; v.y = py[k];
        dst[tid + 256 * k] = v;                 // ds_write_b64
    }
}

// Rolling 5x6 pair-window over an interleaved 36x68 (x,y) tile; 4 rows/thread.
__device__ __forceinline__ void compute_channel(const f2* __restrict__ tile,
                                                int ry, int cx,
                                                float* ch0, float* ch1) {
    const float EPS = 1e-4f;
    const f2 EPS2 = {1e-4f, 1e-4f};
    f2 w[5][6];
    f2 cs[6];

    // prologue: window rows 0..3, init column sums
    #pragma unroll
    for (int k = 0; k < 4; ++k) {
        const int base = (4 * ry + k) * LW + cx;
        const float4 u0 = *reinterpret_cast<const float4*>(&tile[base]);
        const float4 u1 = *reinterpret_cast<const float4*>(&tile[base + 2]);
        const float4 u2 = *reinterpret_cast<const float4*>(&tile[base + 4]);
        w[k][0] = f2{u0.x, u0.y}; w[k][1] = f2{u0.z, u0.w};
        w[k][2] = f2{u1.x, u1.y}; w[k][3] = f2{u1.z, u1.w};
        w[k][4] = f2{u2.x, u2.y}; w[k][5] = f2{u2.z, u2.w};
        #pragma unroll
        for (int j = 0; j < 6; ++j) {
            if (k == 0) cs[j] = w[0][j];
            else        cs[j] += w[k][j];
        }
    }

    #pragma unroll
    for (int o = 0; o < 4; ++o) {
        // load incoming window row o+4 into slot (o+4)%5
        const int sN   = (o + 4) % 5;
        const int base = (4 * ry + o + 4) * LW + cx;
        {
            const float4 u0 = *reinterpret_cast<const float4*>(&tile[base]);
            const float4 u1 = *reinterpret_cast<const float4*>(&tile[base + 2]);
            const float4 u2 = *reinterpret_cast<const float4*>(&tile[base + 4]);
            w[sN][0] = f2{u0.x, u0.y}; w[sN][1] = f2{u0.z, u0.w};
            w[sN][2] = f2{u1.x, u1.y}; w[sN][3] = f2{u1.z, u1.w};
            w[sN][4] = f2{u2.x, u2.y}; w[sN][5] = f2{u2.z, u2.w};
        }
        #pragma unroll
        for (int j = 0; j < 6; ++j) cs[j] += w[sN][j];

        // means for px0 (cols 0..4) and px1 (cols 1..5), both images packed
        const f2 m4 = cs[1] + cs[2] + cs[3] + cs[4];
        const f2 M0 = (m4 + cs[0]) * (1.f / 25.f);   // (mx0, my0)
        const f2 M1 = (m4 + cs[5]) * (1.f / 25.f);   // (mx1, my1)

        float a0 = 0.f, a1 = 0.f;
        #pragma unroll
        for (int k = 0; k < 5; ++k) {
            const int s = (o + k) % 5;
            #pragma unroll
            for (int j = 0; j < 5; ++j) {
                {
                    const f2 d = w[s][j] - M0;                       // pk_add(neg)
                    const float t = d.x * d.y;
                    const float num = fabsf(t) + EPS;
                    const f2 q = __builtin_elementwise_fma(d, d, EPS2); // pk_fma
                    const float den = q.x * q.y;
                    a0 += num * __builtin_amdgcn_rsqf(den);
                }
                {
                    const f2 d = w[s][j + 1] - M1;
                    const float t = d.x * d.y;
                    const float num = fabsf(t) + EPS;
                    const f2 q = __builtin_elementwise_fma(d, d, EPS2);
                    const float den = q.x * q.y;
                    a1 += num * __builtin_amdgcn_rsqf(den);
                }
            }
        }
        ch0[o] += fminf(fmaxf(a0 * (1.f / 25.f), 0.f), 1.f);
        ch1[o] += fminf(fmaxf(a1 * (1.f / 25.f), 0.f), 1.f);

        // retire oldest window row (slot o%5)
        const int sO = o % 5;
        #pragma unroll
        for (int j = 0; j < 6; ++j) cs[j] -= w[sO][j];
    }
}

__global__ __launch_bounds__(256, 2)
void zncc_kernel(const float* __restrict__ x,
                 const float* __restrict__ y,
                 float* __restrict__ out) {
    __shared__ f2 sb[2][LPAD];          // interleaved (x,y) tiles, 40960 B

    const int tid = threadIdx.x;
    const int tx  = tid & 31;           // 32 col-pairs -> 64 cols
    const int ry  = tid >> 5;           // 0..7 -> rows 4*ry..4*ry+3
    const int cx  = 2 * tx;
    const int w0  = blockIdx.x * TW;
    const int h0  = blockIdx.y * TH;
    const int b   = blockIdx.z;

    // staging address math, once (reused for all 3 channels)
    int   goff[NPF];
    float fm[NPF];
    #pragma unroll
    for (int k = 0; k < NPF; ++k) {
        const int i  = tid + 256 * k;
        const int l  = i / LW;
        const int m  = i - l * LW;
        const int gr = h0 + l - HALO;
        const int gc = w0 + m - HALO;
        const bool ok = (i < LSZ) && ((unsigned)gr < (unsigned)H) &&
                        ((unsigned)gc < (unsigned)W);
        goff[k] = ok ? gr * W + gc : 0;
        fm[k]   = ok ? 1.f : 0.f;
    }

    const float* xb0 = x + (size_t)(b * C) * PLANE;
    const float* yb0 = y + (size_t)(b * C) * PLANE;

    float ch0[4] = {0.f, 0.f, 0.f, 0.f};
    float ch1[4] = {0.f, 0.f, 0.f, 0.f};
    float px[NPF], py[NPF];

    // stage channel 0 -> buf0
    prefetch_plane(xb0, yb0, goff, fm, px, py);
    write_tile(&sb[0][0], px, py, tid);
    __syncthreads();

    // channel 0: prefetch ch1, compute from buf0, write buf1
    prefetch_plane(xb0 + PLANE, yb0 + PLANE, goff, fm, px, py);
    compute_channel(&sb[0][0], ry, cx, ch0, ch1);
    write_tile(&sb[1][0], px, py, tid);
    __syncthreads();

    // channel 1: prefetch ch2, compute from buf1, write buf0
    prefetch_plane(xb0 + 2 * PLANE, yb0 + 2 * PLANE, goff, fm, px, py);
    compute_channel(&sb[1][0], ry, cx, ch0, ch1);
    write_tile(&sb[0][0], px, py, tid);
    __syncthreads();

    // channel 2: compute from buf0
    compute_channel(&sb[0][0], ry, cx, ch0, ch1);

    // write 2x4 output strip
    #pragma unroll
    for (int o = 0; o < 4; ++o) {
        float2 v;
        v.x = ch0[o] * (1.f / 3.f);
        v.y = ch1[o] * (1.f / 3.f);
        *reinterpret_cast<float2*>(
            &out[((size_t)b * H + h0 + 4 * ry + o) * W + w0 + cx]) = v;
    }
}

extern "C" void kernel_launch(void* const* d_in, const int* in_sizes, int n_in,
                              void* d_out, int out_size, void* d_ws, size_t ws_size,
                              hipStream_t stream) {
    const float* x = (const float*)d_in[0];
    const float* y = (const float*)d_in[1];
    float* out = (float*)d_out;
    dim3 grid(W / TW, H / TH, NB);   // 8, 16, 4 = 512 blocks (2 per CU)
    zncc_kernel<<<grid, dim3(256), 0, stream>>>(x, y, out);
}

// Round 12
// 29.511 us; speedup vs baseline: 1.1608x; 1.0245x over previous
//
#include <hip/hip_runtime.h>

// ZNCC 5x5, zero-padded, count_include_pad means.
// x,y: (4,3,512,512) f32 -> out: (4,1,512,512) f32
// Round 12: R11 (packed-FP32 on interleaved (x,y) LDS, pipelined dbuf
// staging) + full-window register batching: per channel, all 24
// ds_read_b128 for the thread's 8-row x 6-pair window issue as one
// independent burst, then colsums/means/terms run purely from registers.
// Removes the per-row LDS->colsum->terms serial chain (R10 proved more
// waves don't hide it; this removes the latency from the critical path).

constexpr int W  = 512, H = 512, C = 3, NB = 4;
constexpr int PLANE = H * W;
constexpr int TW = 64, TH = 32, HALO = 2;
constexpr int LW = TW + 2 * HALO;   // 68 pairs per row
constexpr int LH = TH + 2 * HALO;   // 36
constexpr int LSZ  = LW * LH;       // 2448 pairs
constexpr int LPAD = 2560;          // 10 chunks * 256 threads
constexpr int NPF  = 10;

typedef float f2 __attribute__((ext_vector_type(2)));

__device__ __forceinline__ void prefetch_plane(const float* __restrict__ xb,
                                               const float* __restrict__ yb,
                                               const int* goff, const float* fm,
                                               float* px, float* py) {
    #pragma unroll
    for (int k = 0; k < NPF; ++k) {
        px[k] = xb[goff[k]] * fm[k];
        py[k] = yb[goff[k]] * fm[k];
    }
}

__device__ __forceinline__ void write_tile(f2* __restrict__ dst,
                                           const float* px, const float* py,
                                           int tid) {
    #pragma unroll
    for (int k = 0; k < NPF; ++k) {
        f2 v; v.x = px[k]; v.y = py[k];
        dst[tid + 256 * k] = v;                 // ds_write_b64
    }
}

// Full 8-row x 6-pair window batched into registers; rolling colsum in regs.
__device__ __forceinline__ void compute_channel(const f2* __restrict__ tile,
                                                int ry, int cx,
                                                float* ch0, float* ch1) {
    const float EPS = 1e-4f;
    const f2 EPS2 = {1e-4f, 1e-4f};

    // ---- one burst: 24 independent ds_read_b128 ----
    f2 w[8][6];
    #pragma unroll
    for (int k = 0; k < 8; ++k) {
        const int base = (4 * ry + k) * LW + cx;
        const float4 u0 = *reinterpret_cast<const float4*>(&tile[base]);
        const float4 u1 = *reinterpret_cast<const float4*>(&tile[base + 2]);
        const float4 u2 = *reinterpret_cast<const float4*>(&tile[base + 4]);
        w[k][0] = f2{u0.x, u0.y}; w[k][1] = f2{u0.z, u0.w};
        w[k][2] = f2{u1.x, u1.y}; w[k][3] = f2{u1.z, u1.w};
        w[k][4] = f2{u2.x, u2.y}; w[k][5] = f2{u2.z, u2.w};
    }

    // ---- init column sums from rows 0..3 ----
    f2 cs[6];
    #pragma unroll
    for (int j = 0; j < 6; ++j)
        cs[j] = (w[0][j] + w[1][j]) + (w[2][j] + w[3][j]);

    #pragma unroll
    for (int o = 0; o < 4; ++o) {
        #pragma unroll
        for (int j = 0; j < 6; ++j) cs[j] += w[o + 4][j];

        // means for px0 (cols 0..4) and px1 (cols 1..5), both images packed
        const f2 m4 = (cs[1] + cs[2]) + (cs[3] + cs[4]);
        const f2 M0 = (m4 + cs[0]) * (1.f / 25.f);   // (mx0, my0)
        const f2 M1 = (m4 + cs[5]) * (1.f / 25.f);   // (mx1, my1)

        float a0 = 0.f, a1 = 0.f;
        #pragma unroll
        for (int k = 0; k < 5; ++k) {
            #pragma unroll
            for (int j = 0; j < 5; ++j) {
                {
                    const f2 d = w[o + k][j] - M0;                      // pk_add
                    const float t = d.x * d.y;
                    const float num = fabsf(t) + EPS;                   // abs-mod add
                    const f2 q = __builtin_elementwise_fma(d, d, EPS2); // pk_fma
                    const float den = q.x * q.y;
                    a0 += num * __builtin_amdgcn_rsqf(den);
                }
                {
                    const f2 d = w[o + k][j + 1] - M1;
                    const float t = d.x * d.y;
                    const float num = fabsf(t) + EPS;
                    const f2 q = __builtin_elementwise_fma(d, d, EPS2);
                    const float den = q.x * q.y;
                    a1 += num * __builtin_amdgcn_rsqf(den);
                }
            }
        }
        ch0[o] += fminf(fmaxf(a0 * (1.f / 25.f), 0.f), 1.f);
        ch1[o] += fminf(fmaxf(a1 * (1.f / 25.f), 0.f), 1.f);

        #pragma unroll
        for (int j = 0; j < 6; ++j) cs[j] -= w[o][j];
    }
}

__global__ __launch_bounds__(256, 2)
void zncc_kernel(const float* __restrict__ x,
                 const float* __restrict__ y,
                 float* __restrict__ out) {
    __shared__ f2 sb[2][LPAD];          // interleaved (x,y) tiles, 40960 B

    const int tid = threadIdx.x;
    const int tx  = tid & 31;           // 32 col-pairs -> 64 cols
    const int ry  = tid >> 5;           // 0..7 -> rows 4*ry..4*ry+3
    const int cx  = 2 * tx;
    const int w0  = blockIdx.x * TW;
    const int h0  = blockIdx.y * TH;
    const int b   = blockIdx.z;

    // staging address math, once (reused for all 3 channels)
    int   goff[NPF];
    float fm[NPF];
    #pragma unroll
    for (int k = 0; k < NPF; ++k) {
        const int i  = tid + 256 * k;
        const int l  = i / LW;
        const int m  = i - l * LW;
        const int gr = h0 + l - HALO;
        const int gc = w0 + m - HALO;
        const bool ok = (i < LSZ) && ((unsigned)gr < (unsigned)H) &&
                        ((unsigned)gc < (unsigned)W);
        goff[k] = ok ? gr * W + gc : 0;
        fm[k]   = ok ? 1.f : 0.f;
    }

    const float* xb0 = x + (size_t)(b * C) * PLANE;
    const float* yb0 = y + (size_t)(b * C) * PLANE;

    float ch0[4] = {0.f, 0.f, 0.f, 0.f};
    float ch1[4] = {0.f, 0.f, 0.f, 0.f};
    float px[NPF], py[NPF];

    // stage channel 0 -> buf0
    prefetch_plane(xb0, yb0, goff, fm, px, py);
    write_tile(&sb[0][0], px, py, tid);
    __syncthreads();

    // channel 0: prefetch ch1, compute from buf0, write buf1
    prefetch_plane(xb0 + PLANE, yb0 + PLANE, goff, fm, px, py);
    compute_channel(&sb[0][0], ry, cx, ch0, ch1);
    write_tile(&sb[1][0], px, py, tid);
    __syncthreads();

    // channel 1: prefetch ch2, compute from buf1, write buf0
    prefetch_plane(xb0 + 2 * PLANE, yb0 + 2 * PLANE, goff, fm, px, py);
    compute_channel(&sb[1][0], ry, cx, ch0, ch1);
    write_tile(&sb[0][0], px, py, tid);
    __syncthreads();

    // channel 2: compute from buf0
    compute_channel(&sb[0][0], ry, cx, ch0, ch1);

    // write 2x4 output strip
    #pragma unroll
    for (int o = 0; o < 4; ++o) {
        float2 v;
        v.x = ch0[o] * (1.f / 3.f);
        v.y = ch1[o] * (1.f / 3.f);
        *reinterpret_cast<float2*>(
            &out[((size_t)b * H + h0 + 4 * ry + o) * W + w0 + cx]) = v;
    }
}

extern "C" void kernel_launch(void* const* d_in, const int* in_sizes, int n_in,
                              void* d_out, int out_size, void* d_ws, size_t ws_size,
                              hipStream_t stream) {
    const float* x = (const float*)d_in[0];
    const float* y = (const float*)d_in[1];
    float* out = (float*)d_out;
    dim3 grid(W / TW, H / TH, NB);   // 8, 16, 4 = 512 blocks (2 per CU)
    zncc_kernel<<<grid, dim3(256), 0, stream>>>(x, y, out);
}